// Round 8
// baseline (297.942 us; speedup 1.0000x reference)
//
#include <hip/hip_runtime.h>

#define H 1024
#define LEN 8192
#define V 50000
#define CHUNK 8
#define NCH 1024            // chunks per batch
#define NBLK 512
#define NTILE 12500         // V / 4 rows per tile

__device__ __forceinline__ float dot4(float4 a, float4 b) {
    return a.x * b.x + a.y * b.y + a.z * b.z + a.w * b.w;
}

__device__ __forceinline__ void gld_lds16(const float* g, float* l) {
    __builtin_amdgcn_global_load_lds(
        (const __attribute__((address_space(1))) void*)g,
        (__attribute__((address_space(3))) void*)l, 16, 0, 0);
}

// stage 8192 floats (32 KB) global -> LDS, linear, 8 x 16B per thread
__device__ __forceinline__ void stage8k(const float* src, float* dst, int t) {
#pragma unroll
    for (int i = 0; i < 8; ++i)
        gld_lds16(src + i * 1024 + t * 4, dst + i * 1024 + t * 4);
}

// device-scope grid barrier: all NBLK blocks co-resident (2/CU @ 64KB LDS).
// Bounded spin so a residency failure degrades to wrong-answer, not a hang.
__device__ __forceinline__ void gbar(unsigned* ctr) {
    __syncthreads();
    if (threadIdx.x == 0) {
        __threadfence();
        __hip_atomic_fetch_add(ctr, 1u, __ATOMIC_ACQ_REL, __HIP_MEMORY_SCOPE_AGENT);
        long guard = 0;
        while (__hip_atomic_load(ctr, __ATOMIC_ACQUIRE, __HIP_MEMORY_SCOPE_AGENT)
               < (unsigned)NBLK) {
            __builtin_amdgcn_s_sleep(2);
            if (++guard > (1L << 22)) break;   // ~0.2 s safety valve
        }
    }
    __syncthreads();
}

__global__ void __launch_bounds__(256, 2)
k_all(const int* __restrict__ ids,
      const float* __restrict__ emb,
      const float* __restrict__ lctx,
      const float* __restrict__ lhid,
      const float* __restrict__ w_ih,
      const float* __restrict__ w_hh,
      const float* __restrict__ b_ih,
      const float* __restrict__ b_hh,
      const float* __restrict__ attn_w,
      const float* __restrict__ v,
      const float* __restrict__ enc,
      const float* __restrict__ ow,
      const float* __restrict__ ob,
      float* __restrict__ U,
      float* __restrict__ marr,
      float* __restrict__ sarr,
      float* __restrict__ pvec,
      unsigned* __restrict__ bar,
      float* __restrict__ o_output,
      float* __restrict__ o_context,
      float* __restrict__ o_hidden,
      float* __restrict__ o_embedded,
      float* __restrict__ o_rnn) {
    __shared__ float smem[16448];   // 64.25 KB -> 2 blocks/CU
    float* bufA = smem;             // LDS dbuf halves (named, no ptr array:
    float* bufB = smem + 8192;      //  addrspacecast array init won't compile)
    int t    = threadIdx.x;
    int lane = t & 63;
    int wv   = t >> 6;
    int bid  = blockIdx.x;

    // ======================= PHASE 0: u + emb + GRU =======================
    // units: 0..1023 GRU(hh) | 1024..1087 u(16 h's) | 1088..1095 emb
    for (int unit = bid; unit < 1096; unit += NBLK) {
        if (unit < 1024) {
            // ---- GRU cell for output element hh ----
            int hh = unit;
            float* glds = smem;              // [3][4][4] = 48 floats
            int kb = t * 8;
            float4 x0a, x0b, x1a, x1b;
            if (kb < H) {
                const float* p0 = emb + (long)ids[0] * H + kb;
                const float* p1 = emb + (long)ids[1] * H + kb;
                x0a = *(const float4*)p0;  x0b = *(const float4*)(p0 + 4);
                x1a = *(const float4*)p1;  x1b = *(const float4*)(p1 + 4);
            } else {
                const float* p0 = lctx + (kb - H);
                const float* p1 = lctx + H + (kb - H);
                x0a = *(const float4*)p0;  x0b = *(const float4*)(p0 + 4);
                x1a = *(const float4*)p1;  x1b = *(const float4*)(p1 + 4);
            }
            int kb2 = t * 4;
            float4 h0 = *(const float4*)(lhid + kb2);
            float4 h1 = *(const float4*)(lhid + H + kb2);

            for (int g = 0; g < 3; ++g) {
                const float* wi = w_ih + ((long)g * H + hh) * (2 * H) + kb;
                const float* wh = w_hh + ((long)g * H + hh) * H + kb2;
                float4 wa = *(const float4*)wi;
                float4 wb = *(const float4*)(wi + 4);
                float4 wc = *(const float4*)wh;
                float a0 = dot4(wa, x0a) + dot4(wb, x0b);
                float a1 = dot4(wa, x1a) + dot4(wb, x1b);
                float c0 = dot4(wc, h0);
                float c1 = dot4(wc, h1);
                for (int off = 32; off; off >>= 1) {
                    a0 += __shfl_down(a0, off, 64);
                    a1 += __shfl_down(a1, off, 64);
                    c0 += __shfl_down(c0, off, 64);
                    c1 += __shfl_down(c1, off, 64);
                }
                if (lane == 0) {
                    glds[(g * 4 + wv) * 4 + 0] = a0;
                    glds[(g * 4 + wv) * 4 + 1] = a1;
                    glds[(g * 4 + wv) * 4 + 2] = c0;
                    glds[(g * 4 + wv) * 4 + 3] = c1;
                }
            }
            __syncthreads();
            if (t == 0) {
                float gx[3][2], gh[3][2];
                for (int g = 0; g < 3; ++g) {
                    float s0 = 0, s1 = 0, s2 = 0, s3 = 0;
                    for (int w = 0; w < 4; ++w) {
                        s0 += glds[(g * 4 + w) * 4 + 0];
                        s1 += glds[(g * 4 + w) * 4 + 1];
                        s2 += glds[(g * 4 + w) * 4 + 2];
                        s3 += glds[(g * 4 + w) * 4 + 3];
                    }
                    float bi = b_ih[g * H + hh], bh = b_hh[g * H + hh];
                    gx[g][0] = s0 + bi; gx[g][1] = s1 + bi;
                    gh[g][0] = s2 + bh; gh[g][1] = s3 + bh;
                }
                for (int b = 0; b < 2; ++b) {
                    float r  = 1.f / (1.f + expf(-(gx[0][b] + gh[0][b])));
                    float z  = 1.f / (1.f + expf(-(gx[1][b] + gh[1][b])));
                    float n  = tanhf(gx[2][b] + r * gh[2][b]);
                    float hp = lhid[b * H + hh];
                    float hn = (1.f - z) * n + z * hp;
                    o_hidden[b * H + hh] = hn;
                    o_rnn[b * H + hh]    = hn;
                }
            }
            __syncthreads();             // glds reuse by next unit
        } else if (unit < 1088) {
            // ---- u for 16 h's ----
            int ui = unit - 1024;
            float* red = smem + 64;      // 256 floats
            int kg = t >> 4, hi = t & 15;
            int h  = ui * 16 + hi;
            float acc = 0.f;
#pragma unroll 8
            for (int i = 0; i < 64; ++i) {
                int k = kg * 64 + i;
                acc += v[k] * attn_w[(long)k * (2 * H) + H + h];
            }
            red[kg * 16 + hi] = acc;
            __syncthreads();
            if (t < 16) {
                float s = 0.f;
#pragma unroll
                for (int g = 0; g < 16; ++g) s += red[g * 16 + t];
                U[ui * 16 + t] = s;
            }
            __syncthreads();
        } else {
            // ---- embedding gather ----
            int idx = (unit - 1088) * 256 + t;   // 0..2047
            int b = idx >> 10, h = idx & 1023;
            o_embedded[idx] = emb[(long)ids[b] * H + h];
        }
    }
    gbar(bar + 0);

    // ======================= PHASE 1: flash ctx chunks ====================
    {
        float4 uf[4];
#pragma unroll
        for (int c2 = 0; c2 < 4; ++c2)
            uf[c2] = *(const float4*)(U + c2 * 256 + lane * 4);

        stage8k(enc + (long)bid * (CHUNK * H), bufA, t);
        __syncthreads();
        int buf = 0;
        for (int c = bid; c < 2 * NCH; c += NBLK) {     // 4 chunks per block
            int cn = c + NBLK;
            if (cn < 2 * NCH)
                stage8k(enc + (long)cn * (CHUNK * H), buf ? bufA : bufB, t);

            const float* er = buf ? bufB : bufA;
            // energies: every wave computes all 8 (redundant -> no LDS barrier)
            float en8[CHUNK];
#pragma unroll
            for (int r = 0; r < CHUNK; ++r) {
                float acc = 0.f;
#pragma unroll
                for (int c2 = 0; c2 < 4; ++c2) {
                    float4 ev = *(const float4*)(er + r * H + c2 * 256 + lane * 4);
                    acc += dot4(ev, uf[c2]);
                }
#pragma unroll
                for (int off = 32; off; off >>= 1)
                    acc += __shfl_xor(acc, off, 64);
                en8[r] = acc;
            }
            float m = en8[0];
#pragma unroll
            for (int r = 1; r < CHUNK; ++r) m = fmaxf(m, en8[r]);
            float p[CHUNK], s = 0.f;
#pragma unroll
            for (int r = 0; r < CHUNK; ++r) { p[r] = expf(en8[r] - m); s += p[r]; }

            float4 acc4 = {0.f, 0.f, 0.f, 0.f};
#pragma unroll
            for (int r = 0; r < CHUNK; ++r) {
                float4 ev = *(const float4*)(er + r * H + t * 4);
                acc4.x += p[r] * ev.x; acc4.y += p[r] * ev.y;
                acc4.z += p[r] * ev.z; acc4.w += p[r] * ev.w;
            }
            *(float4*)(pvec + (long)c * H + t * 4) = acc4;
            if (t == 0) { marr[c] = m; sarr[c] = s; }

            __syncthreads();            // drains next stage; WAR protect
            buf ^= 1;
        }
    }
    gbar(bar + 1);

    // ======================= PHASE 2: flash combine =======================
    {
        float* scale = smem;            // 1024 floats
        float* rbuf  = smem + 1024;     // scratch
        int idx0 = bid * 4;             // 4 outputs per block
        int b  = idx0 >> 10;
        int hb = idx0 & 1023;
        const float* mb = marr + b * NCH;
        const float* sb = sarr + b * NCH;

        float m = -3.4e38f;
        for (int i = t; i < NCH; i += 256) m = fmaxf(m, mb[i]);
        for (int off = 32; off; off >>= 1) m = fmaxf(m, __shfl_xor(m, off, 64));
        if (lane == 0) rbuf[wv] = m;
        __syncthreads();
        m = fmaxf(fmaxf(rbuf[0], rbuf[1]), fmaxf(rbuf[2], rbuf[3]));
        __syncthreads();

        float d = 0.f;
        for (int i = t; i < NCH; i += 256) {
            float sc = expf(mb[i] - m);
            scale[i] = sc;
            d += sc * sb[i];
        }
        for (int off = 32; off; off >>= 1) d += __shfl_xor(d, off, 64);
        if (lane == 0) rbuf[wv] = d;
        __syncthreads();
        float inv = 1.f / (rbuf[0] + rbuf[1] + rbuf[2] + rbuf[3]);

        float4 acc = {0.f, 0.f, 0.f, 0.f};
        for (int c = t; c < NCH; c += 256) {
            float sc = scale[c];
            float4 pv = *(const float4*)(pvec + ((long)b * NCH + c) * H + hb);
            acc.x += sc * pv.x; acc.y += sc * pv.y;
            acc.z += sc * pv.z; acc.w += sc * pv.w;
        }
        for (int off = 32; off; off >>= 1) {
            acc.x += __shfl_xor(acc.x, off, 64);
            acc.y += __shfl_xor(acc.y, off, 64);
            acc.z += __shfl_xor(acc.z, off, 64);
            acc.w += __shfl_xor(acc.w, off, 64);
        }
        if (lane == 0) *(float4*)(rbuf + 8 + wv * 4) = acc;
        __syncthreads();
        if (t == 0) {
            float4 s0 = *(float4*)(rbuf + 8);
            float4 s1 = *(float4*)(rbuf + 12);
            float4 s2 = *(float4*)(rbuf + 16);
            float4 s3 = *(float4*)(rbuf + 20);
            float4 r;
            r.x = (s0.x + s1.x + s2.x + s3.x) * inv;
            r.y = (s0.y + s1.y + s2.y + s3.y) * inv;
            r.z = (s0.z + s1.z + s2.z + s3.z) * inv;
            r.w = (s0.w + s1.w + s2.w + s3.w) * inv;
            *(float4*)(o_context + idx0) = r;
        }
    }
    gbar(bar + 2);

    // ======================= PHASE 3: output projection ===================
    {
        float4 c0[8], c1[8];
#pragma unroll
        for (int j = 0; j < 8; ++j) {
            int k = (lane + 64 * j) * 4;
            if (j < 4) {
                c0[j] = *(const float4*)(o_hidden + k);
                c1[j] = *(const float4*)(o_hidden + H + k);
            } else {
                c0[j] = *(const float4*)(o_context + (k - H));
                c1[j] = *(const float4*)(o_context + H + (k - H));
            }
        }

        stage8k(ow + (long)bid * 8192, bufA, t);
        __syncthreads();
        int buf = 0;
        for (int T = bid; T < NTILE; T += NBLK) {
            int Tn = T + NBLK;
            if (Tn < NTILE)
                stage8k(ow + (long)Tn * 8192, buf ? bufA : bufB, t);

            const float4* wr = (const float4*)((buf ? bufB : bufA) + wv * (2 * H));
            float a0 = 0.f, a1 = 0.f;
#pragma unroll
            for (int j = 0; j < 8; ++j) {
                float4 w = wr[lane + 64 * j];
                a0 += dot4(w, c0[j]);
                a1 += dot4(w, c1[j]);
            }
            for (int off = 32; off; off >>= 1) {
                a0 += __shfl_down(a0, off, 64);
                a1 += __shfl_down(a1, off, 64);
            }
            if (lane == 0) {
                long row = (long)T * 4 + wv;
                float bb = ob[row];
                o_output[row]     = a0 + bb;
                o_output[V + row] = a1 + bb;
            }
            __syncthreads();
            buf ^= 1;
        }
    }
}

extern "C" void kernel_launch(void* const* d_in, const int* in_sizes, int n_in,
                              void* d_out, int out_size, void* d_ws, size_t ws_size,
                              hipStream_t stream) {
    const int*   ids    = (const int*)  d_in[0];
    const float* lctx   = (const float*)d_in[1];
    const float* lhid   = (const float*)d_in[2];
    const float* enc    = (const float*)d_in[3];
    const float* emb    = (const float*)d_in[4];
    const float* w_ih   = (const float*)d_in[5];
    const float* w_hh   = (const float*)d_in[6];
    const float* b_ih   = (const float*)d_in[7];
    const float* b_hh   = (const float*)d_in[8];
    const float* attn_w = (const float*)d_in[9];
    // d_in[10] = attn_b  (unused: shift-invariant under softmax)
    const float* v      = (const float*)d_in[11];
    const float* out_w  = (const float*)d_in[12];
    const float* out_b  = (const float*)d_in[13];

    float* out_f       = (float*)d_out;
    float* o_output    = out_f;             // (2,1,50000) = 100000
    float* o_context   = out_f + 100000;    // (2,1,1024)  = 2048
    float* o_hidden    = out_f + 102048;    // (1,2,1024)  = 2048
    float* o_embedded  = out_f + 104096;    // (2,1,1024)  = 2048
    float* o_rnn       = out_f + 106144;    // (2,1,1024)  = 2048

    float* ws       = (float*)d_ws;
    unsigned* BAR   = (unsigned*)ws;        // 16 counters (64 B)
    float* U        = ws + 16;              // 1024
    float* MARR     = ws + 16 + 1024;       // 2048
    float* SARR     = ws + 16 + 3072;       // 2048
    float* PVEC     = ws + 16 + 5120;       // 2048*1024 (~8.4 MB total)

    (void)hipMemsetAsync(BAR, 0, 64, stream);
    k_all<<<NBLK, 256, 0, stream>>>(ids, emb, lctx, lhid, w_ih, w_hh,
                                    b_ih, b_hh, attn_w, v, enc,
                                    out_w, out_b,
                                    U, MARR, SARR, PVEC, BAR,
                                    o_output, o_context, o_hidden,
                                    o_embedded, o_rnn);
}

// Round 9
// 126.084 us; speedup vs baseline: 2.3630x; 2.3630x over previous
//
#include <hip/hip_runtime.h>

#define H 1024
#define LEN 8192
#define V 50000
#define CHUNK 8
#define NCH 1024            // ctx chunks per batch
#define NTH 6250            // tiles of 8 rows over V
#define NBC 512             // k_outc persistent blocks

__device__ __forceinline__ float dot4(float4 a, float4 b) {
    return a.x * b.x + a.y * b.y + a.z * b.z + a.w * b.w;
}

__device__ __forceinline__ void gld_lds16(const float* g, float* l) {
    __builtin_amdgcn_global_load_lds(
        (const __attribute__((address_space(1))) void*)g,
        (__attribute__((address_space(3))) void*)l, 16, 0, 0);
}

// stage 8192 contiguous floats (32 KB) global -> LDS
__device__ __forceinline__ void stage8k(const float* src, float* dst, int t) {
#pragma unroll
    for (int i = 0; i < 8; ++i)
        gld_lds16(src + i * 1024 + t * 4, dst + i * 1024 + t * 4);
}

// ---------------------------------------------------------------------------
// K1: fused pre-work (R5-proven).
//   blocks 0..63    : u[h] = sum_k v[k]*attn_w[k*2048+1024+h]
//   blocks 64..71   : embedding gather
//   blocks 72..1095 : GRU cell, one block per output element hh
// ---------------------------------------------------------------------------
__global__ void k_pre(const float* __restrict__ attn_w,
                      const float* __restrict__ v,
                      float* __restrict__ u,
                      const int* __restrict__ ids,
                      const float* __restrict__ emb,
                      float* __restrict__ out_emb,
                      const float* __restrict__ lctx,
                      const float* __restrict__ lhid,
                      const float* __restrict__ w_ih,
                      const float* __restrict__ w_hh,
                      const float* __restrict__ b_ih,
                      const float* __restrict__ b_hh,
                      float* __restrict__ o_hidden,
                      float* __restrict__ o_rnn) {
    __shared__ float red[16][16];
    __shared__ float lds[3][4][4];
    int bid = blockIdx.x;
    int t   = threadIdx.x;

    if (bid < 64) {
        int kg = t >> 4;            // 0..15
        int hi = t & 15;            // 0..15
        int h  = bid * 16 + hi;
        float acc = 0.f;
#pragma unroll 8
        for (int i = 0; i < 64; ++i) {
            int k = kg * 64 + i;
            acc += v[k] * attn_w[(long)k * (2 * H) + H + h];
        }
        red[kg][hi] = acc;
        __syncthreads();
        if (t < 16) {
            float s = 0.f;
#pragma unroll
            for (int g = 0; g < 16; ++g) s += red[g][t];
            u[bid * 16 + t] = s;
        }
        return;
    }
    if (bid < 72) {
        int idx = (bid - 64) * 256 + t;    // 0..2047
        int b = idx >> 10, h = idx & 1023;
        out_emb[idx] = emb[(long)ids[b] * H + h];
        return;
    }

    // ---- GRU ----
    int hh = bid - 72;            // 0..1023
    int kb = t * 8;               // x index base (0..2040)

    float4 x0a, x0b, x1a, x1b;
    if (kb < H) {
        const float* p0 = emb + (long)ids[0] * H + kb;
        const float* p1 = emb + (long)ids[1] * H + kb;
        x0a = *(const float4*)p0;  x0b = *(const float4*)(p0 + 4);
        x1a = *(const float4*)p1;  x1b = *(const float4*)(p1 + 4);
    } else {
        const float* p0 = lctx + (kb - H);
        const float* p1 = lctx + H + (kb - H);
        x0a = *(const float4*)p0;  x0b = *(const float4*)(p0 + 4);
        x1a = *(const float4*)p1;  x1b = *(const float4*)(p1 + 4);
    }
    int kb2 = t * 4;              // h index base (0..1020)
    float4 h0 = *(const float4*)(lhid + kb2);
    float4 h1 = *(const float4*)(lhid + H + kb2);

    for (int g = 0; g < 3; ++g) {
        const float* wi = w_ih + ((long)g * H + hh) * (2 * H) + kb;
        const float* wh = w_hh + ((long)g * H + hh) * H + kb2;
        float4 wa = *(const float4*)wi;
        float4 wb = *(const float4*)(wi + 4);
        float4 wc = *(const float4*)wh;
        float a0 = dot4(wa, x0a) + dot4(wb, x0b);
        float a1 = dot4(wa, x1a) + dot4(wb, x1b);
        float c0 = dot4(wc, h0);
        float c1 = dot4(wc, h1);
        for (int off = 32; off; off >>= 1) {
            a0 += __shfl_down(a0, off, 64);
            a1 += __shfl_down(a1, off, 64);
            c0 += __shfl_down(c0, off, 64);
            c1 += __shfl_down(c1, off, 64);
        }
        if ((t & 63) == 0) {
            int w = t >> 6;
            lds[g][w][0] = a0; lds[g][w][1] = a1;
            lds[g][w][2] = c0; lds[g][w][3] = c1;
        }
    }
    __syncthreads();
    if (t == 0) {
        float gx[3][2], gh[3][2];
        for (int g = 0; g < 3; ++g) {
            float s0 = 0, s1 = 0, s2 = 0, s3 = 0;
            for (int w = 0; w < 4; ++w) {
                s0 += lds[g][w][0]; s1 += lds[g][w][1];
                s2 += lds[g][w][2]; s3 += lds[g][w][3];
            }
            float bi = b_ih[g * H + hh], bh = b_hh[g * H + hh];
            gx[g][0] = s0 + bi; gx[g][1] = s1 + bi;
            gh[g][0] = s2 + bh; gh[g][1] = s3 + bh;
        }
        for (int b = 0; b < 2; ++b) {
            float r  = 1.f / (1.f + expf(-(gx[0][b] + gh[0][b])));
            float z  = 1.f / (1.f + expf(-(gx[1][b] + gh[1][b])));
            float n  = tanhf(gx[2][b] + r * gh[2][b]);
            float hp = lhid[b * H + hh];
            float hn = (1.f - z) * n + z * hp;
            o_hidden[b * H + hh] = hn;
            o_rnn[b * H + hh]    = hn;
        }
    }
}

// ---------------------------------------------------------------------------
// K2: mega-grid of UNIFORM one-shot 32KB blocks — two independent HBM streams:
//   role 0 (2048 blocks): flash ctx chunk (R5-proven body)
//   role 1 (6250 blocks): W_h partial: part[b,row] = hnew_b[0:1024].W[row,0:1024]
// Interleaved 1:3 via bid%4. All blocks stage 32KB once -> 4 blocks/CU.
// grid 8298 x 256
// ---------------------------------------------------------------------------
__global__ void __launch_bounds__(256)
k_mega(const float* __restrict__ enc,
       const float* __restrict__ u,
       float* __restrict__ pvec,
       float* __restrict__ marr,
       float* __restrict__ sarr,
       const float* __restrict__ ow,
       const float* __restrict__ hnew,
       float* __restrict__ part) {
    __shared__ float smem[8200];     // 32.8 KB
    int t    = threadIdx.x;
    int lane = t & 63;
    int wv   = t >> 6;
    int bid  = blockIdx.x;

    int role, idx;
    if (bid < 8192) {
        int r = bid & 3, q = bid >> 2;
        if (r == 0) { role = 0; idx = q; }            // ctx chunks 0..2047
        else        { role = 1; idx = q * 3 + r - 1; } // W_h tiles 0..6143
    } else {
        role = 1; idx = 6144 + (bid - 8192);           // W_h tiles 6144..6249
    }

    if (role == 0) {
        // ---- flash ctx chunk ----
        int b  = idx >> 10;
        int ch = idx & 1023;
        float* erow = smem;              // 8192 floats
        float* elds = smem + 8192;       // 8 floats

        stage8k(enc + ((long)b * LEN + (long)ch * CHUNK) * H, erow, t);

        float4 uf[4];
#pragma unroll
        for (int c = 0; c < 4; ++c)
            uf[c] = *(const float4*)(u + c * 256 + lane * 4);

        __syncthreads();   // staging drained

#pragma unroll
        for (int rr = 0; rr < 2; ++rr) {
            int r = wv * 2 + rr;
            float acc = 0.f;
#pragma unroll
            for (int c = 0; c < 4; ++c) {
                float4 ev = *(const float4*)(erow + r * H + c * 256 + lane * 4);
                acc += dot4(ev, uf[c]);
            }
            for (int off = 32; off; off >>= 1) acc += __shfl_down(acc, off, 64);
            if (lane == 0) elds[r] = acc;
        }
        __syncthreads();

        float m = elds[0];
#pragma unroll
        for (int r = 1; r < CHUNK; ++r) m = fmaxf(m, elds[r]);
        float p[CHUNK], s = 0.f;
#pragma unroll
        for (int r = 0; r < CHUNK; ++r) { p[r] = expf(elds[r] - m); s += p[r]; }

        float4 acc4 = {0.f, 0.f, 0.f, 0.f};
#pragma unroll
        for (int r = 0; r < CHUNK; ++r) {
            float4 ev = *(const float4*)(erow + r * H + t * 4);
            acc4.x += p[r] * ev.x; acc4.y += p[r] * ev.y;
            acc4.z += p[r] * ev.z; acc4.w += p[r] * ev.w;
        }
        *(float4*)(pvec + (long)idx * H + t * 4) = acc4;
        if (t == 0) { marr[idx] = m; sarr[idx] = s; }
        return;
    }

    // ---- W_h partial tile: rows 8*idx .. 8*idx+7, cols 0..1023 ----
    {
        long r0 = (long)idx * 8;
        // stage 8 half-rows (1024 floats each, 16B/lane coalesced)
#pragma unroll
        for (int r = 0; r < 8; ++r)
            gld_lds16(ow + (r0 + r) * (2 * H) + t * 4, smem + r * 1024 + t * 4);

        // hnew halves in registers (L2-hot)
        float4 c0[4], c1[4];
#pragma unroll
        for (int j = 0; j < 4; ++j) {
            c0[j] = ((const float4*)hnew)[lane + 64 * j];
            c1[j] = ((const float4*)(hnew + H))[lane + 64 * j];
        }
        __syncthreads();   // staging drained

        const float4* w4 = (const float4*)smem;
#pragma unroll
        for (int rr = 0; rr < 2; ++rr) {
            int r = wv * 2 + rr;
            float a0 = 0.f, a1 = 0.f;
#pragma unroll
            for (int j = 0; j < 4; ++j) {
                float4 w = w4[r * 256 + lane + 64 * j];
                a0 += dot4(w, c0[j]);
                a1 += dot4(w, c1[j]);
            }
            for (int off = 32; off; off >>= 1) {
                a0 += __shfl_down(a0, off, 64);
                a1 += __shfl_down(a1, off, 64);
            }
            if (lane == 0) {
                long row = r0 + r;
                part[row]     = a0;
                part[V + row] = a1;
            }
        }
    }
}

// ---------------------------------------------------------------------------
// K3: flash combine (R5-proven). 64 blocks; block = (b, 32 h's).
// ---------------------------------------------------------------------------
__global__ void __launch_bounds__(256)
k_red(const float* __restrict__ pvec,
      const float* __restrict__ marr,
      const float* __restrict__ sarr,
      float* __restrict__ out_ctx) {
    __shared__ float scale[NCH];        // 4 KB
    __shared__ float red[8][32];
    int t  = threadIdx.x;
    int b  = blockIdx.x >> 5;           // 0..1
    int h0 = (blockIdx.x & 31) * 32;
    const float* mb = marr + b * NCH;
    const float* sb = sarr + b * NCH;

    float m = -3.4e38f;
    for (int i = t; i < NCH; i += 256) m = fmaxf(m, mb[i]);
    for (int off = 32; off; off >>= 1) m = fmaxf(m, __shfl_xor(m, off, 64));
    if ((t & 63) == 0) red[0][t >> 6] = m;
    __syncthreads();
    m = fmaxf(fmaxf(red[0][0], red[0][1]), fmaxf(red[0][2], red[0][3]));
    __syncthreads();

    float d = 0.f;
    for (int i = t; i < NCH; i += 256) {
        float sc = expf(mb[i] - m);
        scale[i] = sc;
        d += sc * sb[i];
    }
    for (int off = 32; off; off >>= 1) d += __shfl_xor(d, off, 64);
    if ((t & 63) == 0) red[0][t >> 6] = d;
    __syncthreads();
    float inv = 1.f / (red[0][0] + red[0][1] + red[0][2] + red[0][3]);
    __syncthreads();

    int grp = t >> 5, il = t & 31;
    const float* pv = pvec + (long)b * NCH * H + (h0 + il);
    float acc = 0.f;
#pragma unroll 4
    for (int c = grp * 128; c < grp * 128 + 128; ++c)
        acc += scale[c] * pv[(long)c * H];
    red[grp][il] = acc;
    __syncthreads();
    if (t < 32) {
        float ssum = 0.f;
#pragma unroll
        for (int g = 0; g < 8; ++g) ssum += red[g][t];
        out_ctx[b * H + h0 + t] = ssum * inv;
    }
}

// ---------------------------------------------------------------------------
// K4: ctx-half of output projection + partial + bias (persistent dbuf, R5
// k_out pattern). Tiles of 8 rows x 1024 ctx-cols (32KB), 2x32KB LDS,
// ctx halves in registers. grid 512 x 256 (2 blocks/CU).
// ---------------------------------------------------------------------------
__global__ void __launch_bounds__(256)
k_outc(const float* __restrict__ ow,
       const float* __restrict__ ob,
       const float* __restrict__ ctx,
       const float* __restrict__ part,
       float* __restrict__ out) {
    __shared__ float wtA[8 * 1024];   // 32 KB
    __shared__ float wtB[8 * 1024];   // 32 KB
    int t    = threadIdx.x;
    int lane = t & 63;
    int wv   = t >> 6;
    int q    = blockIdx.x;            // 0..511

    float4 c0[4], c1[4];
#pragma unroll
    for (int j = 0; j < 4; ++j) {
        c0[j] = ((const float4*)ctx)[lane + 64 * j];
        c1[j] = ((const float4*)(ctx + H))[lane + 64 * j];
    }

    {
        long r0 = (long)q * 8;
#pragma unroll
        for (int r = 0; r < 8; ++r)
            gld_lds16(ow + (r0 + r) * (2 * H) + H + t * 4, wtA + r * 1024 + t * 4);
    }
    __syncthreads();

    int buf = 0;
    for (int T = q; T < NTH; T += NBC) {
        int Tn = T + NBC;
        if (Tn < NTH) {
            long r0 = (long)Tn * 8;
            float* dst = buf ? wtA : wtB;
#pragma unroll
            for (int r = 0; r < 8; ++r)
                gld_lds16(ow + (r0 + r) * (2 * H) + H + t * 4, dst + r * 1024 + t * 4);
        }
        const float4* w4 = (const float4*)(buf ? wtB : wtA);
#pragma unroll
        for (int rr = 0; rr < 2; ++rr) {
            int r = wv * 2 + rr;
            float a0 = 0.f, a1 = 0.f;
#pragma unroll
            for (int j = 0; j < 4; ++j) {
                float4 w = w4[r * 256 + lane + 64 * j];
                a0 += dot4(w, c0[j]);
                a1 += dot4(w, c1[j]);
            }
            for (int off = 32; off; off >>= 1) {
                a0 += __shfl_down(a0, off, 64);
                a1 += __shfl_down(a1, off, 64);
            }
            if (lane == 0) {
                long row = (long)T * 8 + r;
                float bb = ob[row];
                out[row]     = part[row]     + a0 + bb;
                out[V + row] = part[V + row] + a1 + bb;
            }
        }
        __syncthreads();
        buf ^= 1;
    }
}

extern "C" void kernel_launch(void* const* d_in, const int* in_sizes, int n_in,
                              void* d_out, int out_size, void* d_ws, size_t ws_size,
                              hipStream_t stream) {
    const int*   ids    = (const int*)  d_in[0];
    const float* lctx   = (const float*)d_in[1];
    const float* lhid   = (const float*)d_in[2];
    const float* enc    = (const float*)d_in[3];
    const float* emb    = (const float*)d_in[4];
    const float* w_ih   = (const float*)d_in[5];
    const float* w_hh   = (const float*)d_in[6];
    const float* b_ih   = (const float*)d_in[7];
    const float* b_hh   = (const float*)d_in[8];
    const float* attn_w = (const float*)d_in[9];
    // d_in[10] = attn_b  (unused: shift-invariant under softmax)
    const float* v      = (const float*)d_in[11];
    const float* out_w  = (const float*)d_in[12];
    const float* out_b  = (const float*)d_in[13];

    float* out_f       = (float*)d_out;
    float* o_output    = out_f;             // (2,1,50000) = 100000
    float* o_context   = out_f + 100000;    // (2,1,1024)  = 2048
    float* o_hidden    = out_f + 102048;    // (1,2,1024)  = 2048
    float* o_embedded  = out_f + 104096;    // (2,1,1024)  = 2048
    float* o_rnn       = out_f + 106144;    // (2,1,1024)  = 2048

    float* ws   = (float*)d_ws;
    float* U    = ws;                       // 1024
    float* MARR = ws + 1024;                // 2048
    float* SARR = ws + 3072;                // 2048
    float* PVEC = ws + 5120;                // 2048*1024
    float* PART = ws + 5120 + 2048 * 1024;  // 100000  (~9 MB total)

    k_pre <<<1096, 256, 0, stream>>>(attn_w, v, U, ids, emb, o_embedded,
                                     lctx, lhid, w_ih, w_hh, b_ih, b_hh,
                                     o_hidden, o_rnn);
    k_mega<<<8298, 256, 0, stream>>>(enc, U, PVEC, MARR, SARR,
                                     out_w, o_hidden, PART);
    k_red <<<64,   256, 0, stream>>>(PVEC, MARR, SARR, o_context);
    k_outc<<<512,  256, 0, stream>>>(out_w, out_b, o_context, PART, o_output);
}

// Round 10
// 122.639 us; speedup vs baseline: 2.4294x; 1.0281x over previous
//
#include <hip/hip_runtime.h>

#define H 1024
#define LEN 8192
#define V 50000
#define CHUNK 8
#define NCH 1024            // ctx chunks per batch
#define NBLK 512
#define NTILE 12500         // k_out: V/4 rows per tile

__device__ __forceinline__ float dot4(float4 a, float4 b) {
    return a.x * b.x + a.y * b.y + a.z * b.z + a.w * b.w;
}

__device__ __forceinline__ void gld_lds16(const float* g, float* l) {
    __builtin_amdgcn_global_load_lds(
        (const __attribute__((address_space(1))) void*)g,
        (__attribute__((address_space(3))) void*)l, 16, 0, 0);
}

// stage 8192 contiguous floats (32 KB) global -> LDS (8 x 16B per thread)
__device__ __forceinline__ void stage8k(const float* src, float* dst, int t) {
#pragma unroll
    for (int i = 0; i < 8; ++i)
        gld_lds16(src + i * 1024 + t * 4, dst + i * 1024 + t * 4);
}

// counted waits (T4): keep next tile's 8 loads in flight, drain only oldest 8
__device__ __forceinline__ void wait_vm8() {
    asm volatile("s_waitcnt vmcnt(8)" ::: "memory");
    __builtin_amdgcn_sched_barrier(0);
}
__device__ __forceinline__ void wait_vm0() {
    asm volatile("s_waitcnt vmcnt(0)" ::: "memory");
    __builtin_amdgcn_sched_barrier(0);
}

// ---------------------------------------------------------------------------
// K1: fused pre-work (R5-proven, unchanged).
//   blocks 0..63    : u[h] = sum_k v[k]*attn_w[k*2048+1024+h]
//   blocks 64..71   : embedding gather
//   blocks 72..1095 : GRU cell, one block per output element hh
// ---------------------------------------------------------------------------
__global__ void k_pre(const float* __restrict__ attn_w,
                      const float* __restrict__ v,
                      float* __restrict__ u,
                      const int* __restrict__ ids,
                      const float* __restrict__ emb,
                      float* __restrict__ out_emb,
                      const float* __restrict__ lctx,
                      const float* __restrict__ lhid,
                      const float* __restrict__ w_ih,
                      const float* __restrict__ w_hh,
                      const float* __restrict__ b_ih,
                      const float* __restrict__ b_hh,
                      float* __restrict__ o_hidden,
                      float* __restrict__ o_rnn) {
    __shared__ float red[16][16];
    __shared__ float lds[3][4][4];
    int bid = blockIdx.x;
    int t   = threadIdx.x;

    if (bid < 64) {
        int kg = t >> 4;            // 0..15
        int hi = t & 15;            // 0..15
        int h  = bid * 16 + hi;
        float acc = 0.f;
#pragma unroll 8
        for (int i = 0; i < 64; ++i) {
            int k = kg * 64 + i;
            acc += v[k] * attn_w[(long)k * (2 * H) + H + h];
        }
        red[kg][hi] = acc;
        __syncthreads();
        if (t < 16) {
            float s = 0.f;
#pragma unroll
            for (int g = 0; g < 16; ++g) s += red[g][t];
            u[bid * 16 + t] = s;
        }
        return;
    }
    if (bid < 72) {
        int idx = (bid - 64) * 256 + t;    // 0..2047
        int b = idx >> 10, h = idx & 1023;
        out_emb[idx] = emb[(long)ids[b] * H + h];
        return;
    }

    // ---- GRU ----
    int hh = bid - 72;            // 0..1023
    int kb = t * 8;               // x index base (0..2040)

    float4 x0a, x0b, x1a, x1b;
    if (kb < H) {
        const float* p0 = emb + (long)ids[0] * H + kb;
        const float* p1 = emb + (long)ids[1] * H + kb;
        x0a = *(const float4*)p0;  x0b = *(const float4*)(p0 + 4);
        x1a = *(const float4*)p1;  x1b = *(const float4*)(p1 + 4);
    } else {
        const float* p0 = lctx + (kb - H);
        const float* p1 = lctx + H + (kb - H);
        x0a = *(const float4*)p0;  x0b = *(const float4*)(p0 + 4);
        x1a = *(const float4*)p1;  x1b = *(const float4*)(p1 + 4);
    }
    int kb2 = t * 4;              // h index base (0..1020)
    float4 h0 = *(const float4*)(lhid + kb2);
    float4 h1 = *(const float4*)(lhid + H + kb2);

    for (int g = 0; g < 3; ++g) {
        const float* wi = w_ih + ((long)g * H + hh) * (2 * H) + kb;
        const float* wh = w_hh + ((long)g * H + hh) * H + kb2;
        float4 wa = *(const float4*)wi;
        float4 wb = *(const float4*)(wi + 4);
        float4 wc = *(const float4*)wh;
        float a0 = dot4(wa, x0a) + dot4(wb, x0b);
        float a1 = dot4(wa, x1a) + dot4(wb, x1b);
        float c0 = dot4(wc, h0);
        float c1 = dot4(wc, h1);
        for (int off = 32; off; off >>= 1) {
            a0 += __shfl_down(a0, off, 64);
            a1 += __shfl_down(a1, off, 64);
            c0 += __shfl_down(c0, off, 64);
            c1 += __shfl_down(c1, off, 64);
        }
        if ((t & 63) == 0) {
            int w = t >> 6;
            lds[g][w][0] = a0; lds[g][w][1] = a1;
            lds[g][w][2] = c0; lds[g][w][3] = c1;
        }
    }
    __syncthreads();
    if (t == 0) {
        float gx[3][2], gh[3][2];
        for (int g = 0; g < 3; ++g) {
            float s0 = 0, s1 = 0, s2 = 0, s3 = 0;
            for (int w = 0; w < 4; ++w) {
                s0 += lds[g][w][0]; s1 += lds[g][w][1];
                s2 += lds[g][w][2]; s3 += lds[g][w][3];
            }
            float bi = b_ih[g * H + hh], bh = b_hh[g * H + hh];
            gx[g][0] = s0 + bi; gx[g][1] = s1 + bi;
            gh[g][0] = s2 + bh; gh[g][1] = s3 + bh;
        }
        for (int b = 0; b < 2; ++b) {
            float r  = 1.f / (1.f + expf(-(gx[0][b] + gh[0][b])));
            float z  = 1.f / (1.f + expf(-(gx[1][b] + gh[1][b])));
            float n  = tanhf(gx[2][b] + r * gh[2][b]);
            float hp = lhid[b * H + hh];
            float hn = (1.f - z) * n + z * hp;
            o_hidden[b * H + hh] = hn;
            o_rnn[b * H + hh]    = hn;
        }
    }
}

// ---------------------------------------------------------------------------
// K2: flash ctx chunks — persistent 512 blocks, counted-vmcnt double buffer.
// Each block processes 4 chunks of 8 enc rows (32 KB each). Energies computed
// redundantly per-wave (shfl_xor) so there is no interior barrier; the only
// barriers are the pipeline pair, with vmcnt(8) instead of a full drain.
// ---------------------------------------------------------------------------
__global__ void __launch_bounds__(256)
k_ctx(const float* __restrict__ enc,
      const float* __restrict__ u,
      float* __restrict__ pvec,
      float* __restrict__ marr,
      float* __restrict__ sarr) {
    __shared__ float bufA[CHUNK * H];   // 32 KB
    __shared__ float bufB[CHUNK * H];   // 32 KB
    int t    = threadIdx.x;
    int lane = t & 63;
    int bid  = blockIdx.x;

    float4 uf[4];
#pragma unroll
    for (int c2 = 0; c2 < 4; ++c2)
        uf[c2] = *(const float4*)(u + c2 * 256 + lane * 4);

    stage8k(enc + (long)bid * (CHUNK * H), bufA, t);
    __syncthreads();                    // one-time full drain

    int buf = 0;
    for (int c = bid; c < 2 * NCH; c += NBLK) {
        int cn = c + NBLK;
        if (cn < 2 * NCH) {
            stage8k(enc + (long)cn * (CHUNK * H), buf ? bufA : bufB, t);
            wait_vm8();                 // current landed; next stays in flight
        } else {
            wait_vm0();
        }
        __builtin_amdgcn_s_barrier();   // all waves' current-tile loads landed

        const float* er = buf ? bufB : bufA;
        float en8[CHUNK];
#pragma unroll
        for (int r = 0; r < CHUNK; ++r) {
            float acc = 0.f;
#pragma unroll
            for (int c2 = 0; c2 < 4; ++c2) {
                float4 ev = *(const float4*)(er + r * H + c2 * 256 + lane * 4);
                acc += dot4(ev, uf[c2]);
            }
#pragma unroll
            for (int off = 32; off; off >>= 1)
                acc += __shfl_xor(acc, off, 64);
            en8[r] = acc;
        }
        float m = en8[0];
#pragma unroll
        for (int r = 1; r < CHUNK; ++r) m = fmaxf(m, en8[r]);
        float p[CHUNK], s = 0.f;
#pragma unroll
        for (int r = 0; r < CHUNK; ++r) { p[r] = expf(en8[r] - m); s += p[r]; }

        float4 acc4 = {0.f, 0.f, 0.f, 0.f};
#pragma unroll
        for (int r = 0; r < CHUNK; ++r) {
            float4 ev = *(const float4*)(er + r * H + t * 4);
            acc4.x += p[r] * ev.x; acc4.y += p[r] * ev.y;
            acc4.z += p[r] * ev.z; acc4.w += p[r] * ev.w;
        }
        *(float4*)(pvec + (long)c * H + t * 4) = acc4;
        if (t == 0) { marr[c] = m; sarr[c] = s; }

        __builtin_amdgcn_s_barrier();   // all done reading er before overwrite
        buf ^= 1;
    }
}

// ---------------------------------------------------------------------------
// K3: flash combine (R5-proven, unchanged). 64 blocks; block = (b, 32 h's).
// ---------------------------------------------------------------------------
__global__ void __launch_bounds__(256)
k_red(const float* __restrict__ pvec,
      const float* __restrict__ marr,
      const float* __restrict__ sarr,
      float* __restrict__ out_ctx) {
    __shared__ float scale[NCH];        // 4 KB
    __shared__ float red[8][32];
    int t  = threadIdx.x;
    int b  = blockIdx.x >> 5;           // 0..1
    int h0 = (blockIdx.x & 31) * 32;
    const float* mb = marr + b * NCH;
    const float* sb = sarr + b * NCH;

    float m = -3.4e38f;
    for (int i = t; i < NCH; i += 256) m = fmaxf(m, mb[i]);
    for (int off = 32; off; off >>= 1) m = fmaxf(m, __shfl_xor(m, off, 64));
    if ((t & 63) == 0) red[0][t >> 6] = m;
    __syncthreads();
    m = fmaxf(fmaxf(red[0][0], red[0][1]), fmaxf(red[0][2], red[0][3]));
    __syncthreads();

    float d = 0.f;
    for (int i = t; i < NCH; i += 256) {
        float sc = expf(mb[i] - m);
        scale[i] = sc;
        d += sc * sb[i];
    }
    for (int off = 32; off; off >>= 1) d += __shfl_xor(d, off, 64);
    if ((t & 63) == 0) red[0][t >> 6] = d;
    __syncthreads();
    float inv = 1.f / (red[0][0] + red[0][1] + red[0][2] + red[0][3]);
    __syncthreads();

    int grp = t >> 5, il = t & 31;
    const float* pv = pvec + (long)b * NCH * H + (h0 + il);
    float acc = 0.f;
#pragma unroll 4
    for (int c = grp * 128; c < grp * 128 + 128; ++c)
        acc += scale[c] * pv[(long)c * H];
    red[grp][il] = acc;
    __syncthreads();
    if (t < 32) {
        float ssum = 0.f;
#pragma unroll
        for (int g = 0; g < 8; ++g) ssum += red[g][t];
        out_ctx[b * H + h0 + t] = ssum * inv;
    }
}

// ---------------------------------------------------------------------------
// K4: output projection — R5 structure + counted-vmcnt pipeline.
// Block: cat (16 KB LDS) + 2 x 32 KB dbuf weight tiles (80 KB -> 2 blocks/CU).
// Per tile: [stage next] -> vmcnt(8) -> s_barrier -> compute -> s_barrier.
// HBM queue never drains to zero. grid 512 x 256.
// ---------------------------------------------------------------------------
__global__ void __launch_bounds__(256)
k_out(const float* __restrict__ ow,
      const float* __restrict__ ob,
      const float* __restrict__ hnew,
      const float* __restrict__ ctx,
      float* __restrict__ out) {
    __shared__ float cat0[2 * H];     // 8 KB
    __shared__ float cat1[2 * H];     // 8 KB
    __shared__ float wtA[4 * 2 * H];  // 32 KB
    __shared__ float wtB[4 * 2 * H];  // 32 KB
    int t    = threadIdx.x;
    int lane = t & 63;
    int wv   = t >> 6;

    // prologue: cat into LDS + first tile stage, then one full drain
    {
        float4* c0 = (float4*)cat0;
        float4* c1 = (float4*)cat1;
#pragma unroll
        for (int r = 0; r < 2; ++r) {
            int idx = t + r * 256;         // float4 index 0..511
            int k   = idx * 4;
            if (k < H) {
                c0[idx] = *(const float4*)(hnew + k);
                c1[idx] = *(const float4*)(hnew + H + k);
            } else {
                c0[idx] = *(const float4*)(ctx + (k - H));
                c1[idx] = *(const float4*)(ctx + H + (k - H));
            }
        }
        stage8k(ow + (long)blockIdx.x * 8192, wtA, t);
    }
    __syncthreads();

    const float4* c0 = (const float4*)cat0;
    const float4* c1 = (const float4*)cat1;
    int buf = 0;
    for (int T = blockIdx.x; T < NTILE; T += NBLK) {
        int Tn = T + NBLK;
        if (Tn < NTILE) {
            stage8k(ow + (long)Tn * 8192, buf ? wtA : wtB, t);
            wait_vm8();                 // current tile landed; next in flight
        } else {
            wait_vm0();
        }
        __builtin_amdgcn_s_barrier();

        const float4* wr = (const float4*)((buf ? wtB : wtA) + wv * (2 * H));
        float a0 = 0.f, a1 = 0.f;
#pragma unroll
        for (int j = 0; j < 8; ++j) {
            float4 w = wr[lane + 64 * j];
            a0 += dot4(w, c0[lane + 64 * j]);
            a1 += dot4(w, c1[lane + 64 * j]);
        }
        for (int off = 32; off; off >>= 1) {
            a0 += __shfl_down(a0, off, 64);
            a1 += __shfl_down(a1, off, 64);
        }
        if (lane == 0) {
            long row = (long)T * 4 + wv;
            float bb = ob[row];
            out[row]     = a0 + bb;
            out[V + row] = a1 + bb;
        }
        __builtin_amdgcn_s_barrier();   // readers done before next overwrite
        buf ^= 1;
    }
}

extern "C" void kernel_launch(void* const* d_in, const int* in_sizes, int n_in,
                              void* d_out, int out_size, void* d_ws, size_t ws_size,
                              hipStream_t stream) {
    const int*   ids    = (const int*)  d_in[0];
    const float* lctx   = (const float*)d_in[1];
    const float* lhid   = (const float*)d_in[2];
    const float* enc    = (const float*)d_in[3];
    const float* emb    = (const float*)d_in[4];
    const float* w_ih   = (const float*)d_in[5];
    const float* w_hh   = (const float*)d_in[6];
    const float* b_ih   = (const float*)d_in[7];
    const float* b_hh   = (const float*)d_in[8];
    const float* attn_w = (const float*)d_in[9];
    // d_in[10] = attn_b  (unused: shift-invariant under softmax)
    const float* v      = (const float*)d_in[11];
    const float* out_w  = (const float*)d_in[12];
    const float* out_b  = (const float*)d_in[13];

    float* out_f       = (float*)d_out;
    float* o_output    = out_f;             // (2,1,50000) = 100000
    float* o_context   = out_f + 100000;    // (2,1,1024)  = 2048
    float* o_hidden    = out_f + 102048;    // (1,2,1024)  = 2048
    float* o_embedded  = out_f + 104096;    // (2,1,1024)  = 2048
    float* o_rnn       = out_f + 106144;    // (2,1,1024)  = 2048

    float* ws   = (float*)d_ws;
    float* U    = ws;                       // 1024
    float* MARR = ws + 1024;                // 2048
    float* SARR = ws + 3072;                // 2048
    float* PVEC = ws + 5120;                // 2048*1024 (~8.4 MB total)

    k_pre<<<1096, 256, 0, stream>>>(attn_w, v, U, ids, emb, o_embedded,
                                    lctx, lhid, w_ih, w_hh, b_ih, b_hh,
                                    o_hidden, o_rnn);
    k_ctx<<<NBLK, 256, 0, stream>>>(enc, U, PVEC, MARR, SARR);
    k_red<<<64,   256, 0, stream>>>(PVEC, MARR, SARR, o_context);
    k_out<<<NBLK, 256, 0, stream>>>(out_w, out_b, o_hidden, o_context,
                                    o_output);
}

// Round 11
// 108.518 us; speedup vs baseline: 2.7456x; 1.1301x over previous
//
#include <hip/hip_runtime.h>

#define H 1024
#define LEN 8192
#define V 50000
#define NTILE 12500   // k_out: V/4 rows per tile
#define NBO 500       // k_out blocks: 12500/500 = exactly 25 tiles each
#define CHUNK 8
#define NCH (LEN / CHUNK)   // 1024 chunks per batch

__device__ __forceinline__ float dot4(float4 a, float4 b) {
    return a.x * b.x + a.y * b.y + a.z * b.z + a.w * b.w;
}

__device__ __forceinline__ void gld_lds16(const float* g, float* l) {
    __builtin_amdgcn_global_load_lds(
        (const __attribute__((address_space(1))) void*)g,
        (__attribute__((address_space(3))) void*)l, 16, 0, 0);
}

// ---------------------------------------------------------------------------
// K1: fused pre-work (R5-proven, unchanged).
//   blocks 0..63    : u[h] = sum_k v[k]*attn_w[k*2048+1024+h]
//   blocks 64..71   : embedding gather
//   blocks 72..1095 : GRU cell, one block per output element hh
// ---------------------------------------------------------------------------
__global__ void k_pre(const float* __restrict__ attn_w,
                      const float* __restrict__ v,
                      float* __restrict__ u,
                      const int* __restrict__ ids,
                      const float* __restrict__ emb,
                      float* __restrict__ out_emb,
                      const float* __restrict__ lctx,
                      const float* __restrict__ lhid,
                      const float* __restrict__ w_ih,
                      const float* __restrict__ w_hh,
                      const float* __restrict__ b_ih,
                      const float* __restrict__ b_hh,
                      float* __restrict__ o_hidden,
                      float* __restrict__ o_rnn) {
    __shared__ float red[16][16];
    __shared__ float lds[3][4][4];
    int bid = blockIdx.x;
    int t   = threadIdx.x;

    if (bid < 64) {
        int kg = t >> 4;            // 0..15
        int hi = t & 15;            // 0..15
        int h  = bid * 16 + hi;
        float acc = 0.f;
#pragma unroll 8
        for (int i = 0; i < 64; ++i) {
            int k = kg * 64 + i;
            acc += v[k] * attn_w[(long)k * (2 * H) + H + h];
        }
        red[kg][hi] = acc;
        __syncthreads();
        if (t < 16) {
            float s = 0.f;
#pragma unroll
            for (int g = 0; g < 16; ++g) s += red[g][t];
            u[bid * 16 + t] = s;
        }
        return;
    }
    if (bid < 72) {
        int idx = (bid - 64) * 256 + t;    // 0..2047
        int b = idx >> 10, h = idx & 1023;
        out_emb[idx] = emb[(long)ids[b] * H + h];
        return;
    }

    // ---- GRU ----
    int hh = bid - 72;            // 0..1023
    int kb = t * 8;               // x index base (0..2040)

    float4 x0a, x0b, x1a, x1b;
    if (kb < H) {
        const float* p0 = emb + (long)ids[0] * H + kb;
        const float* p1 = emb + (long)ids[1] * H + kb;
        x0a = *(const float4*)p0;  x0b = *(const float4*)(p0 + 4);
        x1a = *(const float4*)p1;  x1b = *(const float4*)(p1 + 4);
    } else {
        const float* p0 = lctx + (kb - H);
        const float* p1 = lctx + H + (kb - H);
        x0a = *(const float4*)p0;  x0b = *(const float4*)(p0 + 4);
        x1a = *(const float4*)p1;  x1b = *(const float4*)(p1 + 4);
    }
    int kb2 = t * 4;              // h index base (0..1020)
    float4 h0 = *(const float4*)(lhid + kb2);
    float4 h1 = *(const float4*)(lhid + H + kb2);

    for (int g = 0; g < 3; ++g) {
        const float* wi = w_ih + ((long)g * H + hh) * (2 * H) + kb;
        const float* wh = w_hh + ((long)g * H + hh) * H + kb2;
        float4 wa = *(const float4*)wi;
        float4 wb = *(const float4*)(wi + 4);
        float4 wc = *(const float4*)wh;
        float a0 = dot4(wa, x0a) + dot4(wb, x0b);
        float a1 = dot4(wa, x1a) + dot4(wb, x1b);
        float c0 = dot4(wc, h0);
        float c1 = dot4(wc, h1);
        for (int off = 32; off; off >>= 1) {
            a0 += __shfl_down(a0, off, 64);
            a1 += __shfl_down(a1, off, 64);
            c0 += __shfl_down(c0, off, 64);
            c1 += __shfl_down(c1, off, 64);
        }
        if ((t & 63) == 0) {
            int w = t >> 6;
            lds[g][w][0] = a0; lds[g][w][1] = a1;
            lds[g][w][2] = c0; lds[g][w][3] = c1;
        }
    }
    __syncthreads();
    if (t == 0) {
        float gx[3][2], gh[3][2];
        for (int g = 0; g < 3; ++g) {
            float s0 = 0, s1 = 0, s2 = 0, s3 = 0;
            for (int w = 0; w < 4; ++w) {
                s0 += lds[g][w][0]; s1 += lds[g][w][1];
                s2 += lds[g][w][2]; s3 += lds[g][w][3];
            }
            float bi = b_ih[g * H + hh], bh = b_hh[g * H + hh];
            gx[g][0] = s0 + bi; gx[g][1] = s1 + bi;
            gh[g][0] = s2 + bh; gh[g][1] = s3 + bh;
        }
        for (int b = 0; b < 2; ++b) {
            float r  = 1.f / (1.f + expf(-(gx[0][b] + gh[0][b])));
            float z  = 1.f / (1.f + expf(-(gx[1][b] + gh[1][b])));
            float n  = tanhf(gx[2][b] + r * gh[2][b]);
            float hp = lhid[b * H + hh];
            float hn = (1.f - z) * n + z * hp;
            o_hidden[b * H + hh] = hn;
            o_rnn[b * H + hh]    = hn;
        }
    }
}

// ---------------------------------------------------------------------------
// K2: flash-style context partials (R5-proven, unchanged). Block = chunk of 8.
// grid 2048 x 256
// ---------------------------------------------------------------------------
__global__ void __launch_bounds__(256)
k_ctx(const float* __restrict__ enc,
      const float* __restrict__ u,
      float* __restrict__ pvec,
      float* __restrict__ marr,
      float* __restrict__ sarr) {
    __shared__ float erow[CHUNK * H];    // 32 KB
    __shared__ float elds[CHUNK];
    int t    = threadIdx.x;
    int lane = t & 63;
    int wv   = t >> 6;
    int b    = blockIdx.x >> 10;         // 0..1
    int ch   = blockIdx.x & 1023;        // 0..1023

    const float* src = enc + ((long)b * LEN + (long)ch * CHUNK) * H;
#pragma unroll
    for (int i = 0; i < CHUNK; ++i)
        gld_lds16(src + i * H + t * 4, erow + i * H + t * 4);

    float4 uf[4];
#pragma unroll
    for (int c = 0; c < 4; ++c)
        uf[c] = *(const float4*)(u + c * 256 + lane * 4);

    __syncthreads();   // staging drained

#pragma unroll
    for (int rr = 0; rr < 2; ++rr) {
        int r = wv * 2 + rr;
        float acc = 0.f;
#pragma unroll
        for (int c = 0; c < 4; ++c) {
            float4 ev = *(const float4*)(erow + r * H + c * 256 + lane * 4);
            acc += dot4(ev, uf[c]);
        }
        for (int off = 32; off; off >>= 1) acc += __shfl_down(acc, off, 64);
        if (lane == 0) elds[r] = acc;
    }
    __syncthreads();

    float m = elds[0];
#pragma unroll
    for (int r = 1; r < CHUNK; ++r) m = fmaxf(m, elds[r]);
    float p[CHUNK];
    float s = 0.f;
#pragma unroll
    for (int r = 0; r < CHUNK; ++r) { p[r] = expf(elds[r] - m); s += p[r]; }

    float4 acc = {0.f, 0.f, 0.f, 0.f};
#pragma unroll
    for (int r = 0; r < CHUNK; ++r) {
        float4 ev = *(const float4*)(erow + r * H + t * 4);
        acc.x += p[r] * ev.x; acc.y += p[r] * ev.y;
        acc.z += p[r] * ev.z; acc.w += p[r] * ev.w;
    }
    *(float4*)(pvec + (long)blockIdx.x * H + t * 4) = acc;
    if (t == 0) { marr[blockIdx.x] = m; sarr[blockIdx.x] = s; }
}

// ---------------------------------------------------------------------------
// K3: flash combine — VECTORIZED. 64 blocks; block = (b, 32 h's).
// Weighted-sum phase: thread owns float4 h-slice (hq=t&7), chunk-lane t>>3;
// 32 fully-unrolled float4 loads (128B-coalesced, deep ILP) replace R5's
// 4B-strided serial chain (latency-bound, ~2x under BW).
// ---------------------------------------------------------------------------
__global__ void __launch_bounds__(256)
k_red(const float* __restrict__ pvec,
      const float* __restrict__ marr,
      const float* __restrict__ sarr,
      float* __restrict__ out_ctx) {
    __shared__ float scale[NCH];        // 4 KB
    __shared__ float rbuf[4];
    __shared__ float4 part[32][8];      // 4 KB
    int t  = threadIdx.x;
    int b  = blockIdx.x >> 5;           // 0..1
    int h0 = (blockIdx.x & 31) * 32;
    const float* mb = marr + b * NCH;
    const float* sb = sarr + b * NCH;

    float m = -3.4e38f;
    for (int i = t; i < NCH; i += 256) m = fmaxf(m, mb[i]);
    for (int off = 32; off; off >>= 1) m = fmaxf(m, __shfl_xor(m, off, 64));
    if ((t & 63) == 0) rbuf[t >> 6] = m;
    __syncthreads();
    m = fmaxf(fmaxf(rbuf[0], rbuf[1]), fmaxf(rbuf[2], rbuf[3]));
    __syncthreads();

    float d = 0.f;
    for (int i = t; i < NCH; i += 256) {
        float sc = expf(mb[i] - m);
        scale[i] = sc;
        d += sc * sb[i];
    }
    for (int off = 32; off; off >>= 1) d += __shfl_xor(d, off, 64);
    if ((t & 63) == 0) rbuf[t >> 6] = d;
    __syncthreads();
    float inv = 1.f / (rbuf[0] + rbuf[1] + rbuf[2] + rbuf[3]);

    // weighted sum: hq = float4-slice of the 32 h's; clane = chunk lane
    int hq    = t & 7;                  // 0..7
    int clane = t >> 3;                 // 0..31
    const float* pv = pvec + (long)b * NCH * H + h0 + hq * 4;
    float4 acc = {0.f, 0.f, 0.f, 0.f};
#pragma unroll
    for (int k = 0; k < 32; ++k) {
        int c = clane + 32 * k;
        float sc = scale[c];
        float4 p = *(const float4*)(pv + (long)c * H);
        acc.x += sc * p.x; acc.y += sc * p.y;
        acc.z += sc * p.z; acc.w += sc * p.w;
    }
    part[clane][hq] = acc;
    __syncthreads();
    if (t < 8) {
        float4 s4 = {0.f, 0.f, 0.f, 0.f};
#pragma unroll
        for (int c = 0; c < 32; ++c) {
            float4 p = part[c][t];
            s4.x += p.x; s4.y += p.y; s4.z += p.z; s4.w += p.w;
        }
        s4.x *= inv; s4.y *= inv; s4.z *= inv; s4.w *= inv;
        *(float4*)(out_ctx + b * H + h0 + t * 4) = s4;
    }
}

// ---------------------------------------------------------------------------
// K4: output projection (R5-proven structure). grid 500 x 256 -> exactly 25
// tiles per block, uniform finish (no 212-block straggler tail).
// ---------------------------------------------------------------------------
__global__ void __launch_bounds__(256)
k_out(const float* __restrict__ ow,
      const float* __restrict__ ob,
      const float* __restrict__ hnew,
      const float* __restrict__ ctx,
      float* __restrict__ out) {
    __shared__ float cat[2][2 * H];       // 16 KB
    __shared__ float wt[2][4 * 2 * H];    // 64 KB
    int t    = threadIdx.x;
    int lane = t & 63;
    int wv   = t >> 6;

    {
        float4* c0 = (float4*)cat[0];
        float4* c1 = (float4*)cat[1];
#pragma unroll
        for (int r = 0; r < 2; ++r) {
            int idx = t + r * 256;
            int k   = idx * 4;
            if (k < H) {
                c0[idx] = *(const float4*)(hnew + k);
                c1[idx] = *(const float4*)(hnew + H + k);
            } else {
                c0[idx] = *(const float4*)(ctx + (k - H));
                c1[idx] = *(const float4*)(ctx + H + (k - H));
            }
        }
    }
    {
        const float* src = ow + (long)blockIdx.x * (4 * 2 * H);
#pragma unroll
        for (int i = 0; i < 8; ++i)
            gld_lds16(src + i * 1024 + t * 4, wt[0] + i * 1024 + t * 4);
    }
    __syncthreads();

    const float4* c0 = (const float4*)cat[0];
    const float4* c1 = (const float4*)cat[1];
    int buf = 0;
    for (int T = blockIdx.x; T < NTILE; T += NBO) {
        int Tn = T + NBO;
        if (Tn < NTILE) {
            const float* src = ow + (long)Tn * (4 * 2 * H);
            float* dst = wt[buf ^ 1];
#pragma unroll
            for (int i = 0; i < 8; ++i)
                gld_lds16(src + i * 1024 + t * 4, dst + i * 1024 + t * 4);
        }
        const float4* wr = (const float4*)(wt[buf] + wv * (2 * H));
        float a0 = 0.f, a1 = 0.f;
#pragma unroll
        for (int j = 0; j < 8; ++j) {
            float4 w = wr[lane + 64 * j];
            a0 += dot4(w, c0[lane + 64 * j]);
            a1 += dot4(w, c1[lane + 64 * j]);
        }
        for (int off = 32; off; off >>= 1) {
            a0 += __shfl_down(a0, off, 64);
            a1 += __shfl_down(a1, off, 64);
        }
        if (lane == 0) {
            long row = (long)T * 4 + wv;
            float bb = ob[row];
            out[row]     = a0 + bb;
            out[V + row] = a1 + bb;
        }
        __syncthreads();
        buf ^= 1;
    }
}

extern "C" void kernel_launch(void* const* d_in, const int* in_sizes, int n_in,
                              void* d_out, int out_size, void* d_ws, size_t ws_size,
                              hipStream_t stream) {
    const int*   ids    = (const int*)  d_in[0];
    const float* lctx   = (const float*)d_in[1];
    const float* lhid   = (const float*)d_in[2];
    const float* enc    = (const float*)d_in[3];
    const float* emb    = (const float*)d_in[4];
    const float* w_ih   = (const float*)d_in[5];
    const float* w_hh   = (const float*)d_in[6];
    const float* b_ih   = (const float*)d_in[7];
    const float* b_hh   = (const float*)d_in[8];
    const float* attn_w = (const float*)d_in[9];
    // d_in[10] = attn_b  (unused: shift-invariant under softmax)
    const float* v      = (const float*)d_in[11];
    const float* out_w  = (const float*)d_in[12];
    const float* out_b  = (const float*)d_in[13];

    float* out_f       = (float*)d_out;
    float* o_output    = out_f;             // (2,1,50000) = 100000
    float* o_context   = out_f + 100000;    // (2,1,1024)  = 2048
    float* o_hidden    = out_f + 102048;    // (1,2,1024)  = 2048
    float* o_embedded  = out_f + 104096;    // (2,1,1024)  = 2048
    float* o_rnn       = out_f + 106144;    // (2,1,1024)  = 2048

    float* ws   = (float*)d_ws;
    float* U    = ws;                    // 1024
    float* MARR = ws + 1024;             // 2048
    float* SARR = ws + 3072;             // 2048
    float* PVEC = ws + 5120;             // 2048*1024 (~8.4 MB total)

    k_pre<<<1096, 256, 0, stream>>>(attn_w, v, U, ids, emb, o_embedded,
                                    lctx, lhid, w_ih, w_hh, b_ih, b_hh,
                                    o_hidden, o_rnn);
    k_ctx<<<2048, 256, 0, stream>>>(enc, U, PVEC, MARR, SARR);
    k_red<<<64,   256, 0, stream>>>(PVEC, MARR, SARR, o_context);
    k_out<<<NBO,  256, 0, stream>>>(out_w, out_b, o_hidden, o_context,
                                    o_output);
}